// Round 1
// baseline (180.408 us; speedup 1.0000x reference)
//
#include <hip/hip_runtime.h>
#include <hip/hip_bf16.h>

// Problem constants
#define B_SZ 256
#define SDIM 1024
#define ADIM 512

// GEMM tile config for khyper
#define BK 32
#define BM 256          // all batch rows per block
#define BN 160          // 128 h-rows + row128 = bias row (weight 1) + 31 pad rows (weight 0)
#define PAD 36          // padded LDS row length (elements); 72B row stride -> <=2-way bank conflicts
#define NSTEPS (SDIM / BK)

typedef __attribute__((ext_vector_type(8))) short bf16x8;
typedef __attribute__((ext_vector_type(4))) short bf16x4;
typedef __attribute__((ext_vector_type(4))) float f32x4;

__device__ __forceinline__ unsigned short f2bf(float x) {
  union { float f; unsigned u; } v; v.f = x;
  unsigned r = v.u + 0x7FFFu + ((v.u >> 16) & 1u);   // round-to-nearest-even
  return (unsigned short)(r >> 16);
}

// ---------------- Kernel 1: small MLPs ----------------
__global__ __launch_bounds__(128) void kprep(
    const float* __restrict__ task, const int* __restrict__ action,
    const float* __restrict__ we1, const float* __restrict__ be1,
    const float* __restrict__ we2, const float* __restrict__ be2,
    const float* __restrict__ aw1, const float* __restrict__ aw1b,
    const float* __restrict__ ab1, const float* __restrict__ ab1b,
    const float* __restrict__ ab2, const float* __restrict__ ab2b,
    const float* __restrict__ cw1, const float* __restrict__ cw1b,
    const float* __restrict__ cb1, const float* __restrict__ cb1b,
    const float* __restrict__ cb2, const float* __restrict__ cb2b,
    float* __restrict__ ws_ha, float* __restrict__ ws_hc,
    float* __restrict__ out)
{
  const int b = blockIdx.x, t = threadIdx.x;
  __shared__ float s_task[64], s_t1[64], s_z[64], s_hb[128], s_red[128];

  if (t < 64) s_task[t] = task[b * 64 + t];
  __syncthreads();
  if (t < 64) {
    float a = be1[t];
    for (int e = 0; e < 64; ++e) a += s_task[e] * we1[e * 64 + t];
    s_t1[t] = fmaxf(a, 0.0f);
  }
  __syncthreads();
  if (t < 64) {
    float a = be2[t];
    for (int e = 0; e < 64; ++e) a += s_t1[e] * we2[e * 64 + t];
    s_z[t] = fmaxf(a, 0.0f);
  }
  __syncthreads();
  {
    float a1 = aw1b[t], a2 = ab1b[t], a3 = cw1b[t], a4 = cb1b[t];
    for (int e = 0; e < 64; ++e) {
      const float zv = s_z[e];
      a1 += zv * aw1[e * 128 + t];
      a2 += zv * ab1[e * 128 + t];
      a3 += zv * cw1[e * 128 + t];
      a4 += zv * cb1[e * 128 + t];
    }
    ws_ha[b * 128 + t] = fmaxf(a1, 0.0f);
    s_hb[t] = fmaxf(a2, 0.0f);
    ws_hc[b * 128 + t] = fmaxf(a3, 0.0f);
    s_red[t] = fmaxf(a4, 0.0f) * cb2[t];   // cb2 is [128,1]
  }
  __syncthreads();
  // ba -> staged into d_out logits slots (khyper accumulates on top)
  for (int o = t; o < ADIM; o += 128) {
    float a = ab2b[o];
    for (int h = 0; h < 128; ++h) a += s_hb[h] * ab2[h * ADIM + o];
    out[b * ADIM + o] = a;
  }
  // bv reduction
  for (int s = 64; s > 0; s >>= 1) {
    __syncthreads();
    if (t < s) s_red[t] += s_red[t + s];
  }
  if (t == 0) {
    out[131840 + b] = s_red[0] + cb2b[0];      // partial v (bv); critic block adds the rest
    out[131072 + b] = (float)action[b];        // action as float
  }
}

// ---------------- Kernel 2: hypernet heavy GEMM + h-reduction ----------------
__global__ __launch_bounds__(512) void khyper(
    const float* __restrict__ obs,
    const float* __restrict__ aw2, const float* __restrict__ aw2b,
    const float* __restrict__ cw2, const float* __restrict__ cw2b,
    const float* __restrict__ ws_ha, const float* __restrict__ ws_hc,
    float* __restrict__ d_out)
{
  __shared__ unsigned short A_lds[2][BM][PAD];
  __shared__ unsigned short B_lds[2][BN][PAD];
  __shared__ float logits_buf[BM];

  const int tid = threadIdx.x;
  const int blk = blockIdx.x;
  const bool critic = (blk >= ADIM);
  const int o = critic ? 0 : blk;
  const float* Wmat = critic ? cw2 : aw2;
  const long wstride = critic ? (long)SDIM : (long)ADIM * SDIM;
  const float* bias_row = (critic ? cw2b : aw2b) + (long)o * SDIM;
  const float* haW = critic ? ws_hc : ws_ha;

  // A staging: 2048 float4 per step / 512 threads = 4 each
  const float* aptr[4];
  int aoff[4];
#pragma unroll
  for (int i = 0; i < 4; ++i) {
    const int idx = tid + i * 512;
    const int row = idx >> 3, c4 = idx & 7;
    aptr[i] = obs + (long)row * SDIM + c4 * 4;
    aoff[i] = row * PAD + c4 * 4;
  }
  // B staging: 1280 float4 per step -> threads <256 do 3, rest do 2
  const float* bptr[3];
  int boff[3];
#pragma unroll
  for (int i = 0; i < 3; ++i) {
    const int idx = tid + i * 512;
    const int row = idx >> 3, c4 = idx & 7;
    if (row < 128) bptr[i] = Wmat + (long)row * wstride + (long)o * SDIM + c4 * 4;
    else           bptr[i] = bias_row + c4 * 4;   // synthetic bias row(s)
    boff[i] = row * PAD + c4 * 4;
  }

  const int lane = tid & 63;
  const int wv = tid >> 6;
  const int mbase = (wv & 3) * 64;    // 4 waves over M=256
  const int nbase = (wv >> 2) * 80;   // 2 waves over N=160
  const int lrow = lane & 15;
  const int lk = (lane >> 4) * 8;

  f32x4 acc[4][5];
#pragma unroll
  for (int mf = 0; mf < 4; ++mf)
#pragma unroll
    for (int nf = 0; nf < 5; ++nf) acc[mf][nf] = (f32x4)(0.0f);

  float4 aR[4]; float4 bR[3];

  auto load_step = [&](int t) {
    const int k0 = t * BK;
#pragma unroll
    for (int i = 0; i < 4; ++i) aR[i] = *(const float4*)(aptr[i] + k0);
#pragma unroll
    for (int i = 0; i < 2; ++i) bR[i] = *(const float4*)(bptr[i] + k0);
    if (tid < 256) bR[2] = *(const float4*)(bptr[2] + k0);
  };

  auto store_step = [&](int buf) {
    unsigned short* Ab = &A_lds[buf][0][0];
    unsigned short* Bb = &B_lds[buf][0][0];
#pragma unroll
    for (int i = 0; i < 4; ++i) {
      ushort4 p; p.x = f2bf(aR[i].x); p.y = f2bf(aR[i].y); p.z = f2bf(aR[i].z); p.w = f2bf(aR[i].w);
      *(ushort4*)(Ab + aoff[i]) = p;
    }
#pragma unroll
    for (int i = 0; i < 2; ++i) {
      ushort4 p; p.x = f2bf(bR[i].x); p.y = f2bf(bR[i].y); p.z = f2bf(bR[i].z); p.w = f2bf(bR[i].w);
      *(ushort4*)(Bb + boff[i]) = p;
    }
    if (tid < 256) {
      ushort4 p; p.x = f2bf(bR[2].x); p.y = f2bf(bR[2].y); p.z = f2bf(bR[2].z); p.w = f2bf(bR[2].w);
      *(ushort4*)(Bb + boff[2]) = p;
    }
  };

  auto compute_step = [&](int buf) {
    const unsigned short* Ab = &A_lds[buf][0][0];
    const unsigned short* Bb = &B_lds[buf][0][0];
    union U8 { bf16x8 v8; bf16x4 v4[2]; };
    bf16x8 af[4]; bf16x8 bfr[5];
#pragma unroll
    for (int mf = 0; mf < 4; ++mf) {
      const unsigned short* p = Ab + (mbase + mf * 16 + lrow) * PAD + lk;
      U8 u; u.v4[0] = *(const bf16x4*)p; u.v4[1] = *(const bf16x4*)(p + 4);
      af[mf] = u.v8;
    }
#pragma unroll
    for (int nf = 0; nf < 5; ++nf) {
      const unsigned short* p = Bb + (nbase + nf * 16 + lrow) * PAD + lk;
      U8 u; u.v4[0] = *(const bf16x4*)p; u.v4[1] = *(const bf16x4*)(p + 4);
      bfr[nf] = u.v8;
    }
#pragma unroll
    for (int mf = 0; mf < 4; ++mf)
#pragma unroll
      for (int nf = 0; nf < 5; ++nf)
        acc[mf][nf] = __builtin_amdgcn_mfma_f32_16x16x32_bf16(af[mf], bfr[nf], acc[mf][nf], 0, 0, 0);
  };

  // Pipeline: one barrier per K-step, loads issued one step ahead
  load_step(0);
  store_step(0);
  __syncthreads();
  int cur = 0;
#pragma unroll 2
  for (int t = 0; t < NSTEPS; ++t) {
    if (t + 1 < NSTEPS) load_step(t + 1);
    compute_step(cur);
    if (t + 1 < NSTEPS) store_step(cur ^ 1);
    __syncthreads();
    cur ^= 1;
  }

  // Epilogue: logits[b] = sum_h weight(h) * G[b,h]
  if (tid < BM) logits_buf[tid] = 0.0f;
  __syncthreads();

  float val[4][4];
#pragma unroll
  for (int mf = 0; mf < 4; ++mf)
#pragma unroll
    for (int r = 0; r < 4; ++r) val[mf][r] = 0.0f;

#pragma unroll
  for (int nf = 0; nf < 5; ++nf) {
    const int hidx = nbase + nf * 16 + lrow;
    if (hidx < 128) {
#pragma unroll
      for (int mf = 0; mf < 4; ++mf) {
        const int m0 = mbase + mf * 16 + ((lane >> 4) << 2);
#pragma unroll
        for (int r = 0; r < 4; ++r)
          val[mf][r] += haW[(m0 + r) * 128 + hidx] * acc[mf][nf][r];
      }
    } else if (hidx == 128) {   // bias row: weight 1
#pragma unroll
      for (int mf = 0; mf < 4; ++mf)
#pragma unroll
        for (int r = 0; r < 4; ++r) val[mf][r] += acc[mf][nf][r];
    }
  }

#pragma unroll
  for (int mf = 0; mf < 4; ++mf)
#pragma unroll
    for (int r = 0; r < 4; ++r) {
      float v = val[mf][r];
      v += __shfl_xor(v, 1, 64);
      v += __shfl_xor(v, 2, 64);
      v += __shfl_xor(v, 4, 64);
      v += __shfl_xor(v, 8, 64);
      val[mf][r] = v;
    }
  if ((lane & 15) == 0) {
#pragma unroll
    for (int mf = 0; mf < 4; ++mf)
#pragma unroll
      for (int r = 0; r < 4; ++r)
        atomicAdd(&logits_buf[mbase + mf * 16 + ((lane >> 4) << 2) + r], val[mf][r]);
  }
  __syncthreads();

  if (tid < BM) {
    if (!critic) {
      float* p = d_out + (long)tid * ADIM + o;   // ba was pre-staged here by kprep
      *p += logits_buf[tid];
    } else {
      d_out[131840 + tid] += logits_buf[tid];    // v = bv(partial) + sum_h hc*G
    }
  }
}

// ---------------- Kernel 3: log_softmax / entropy / log_prob ----------------
__global__ __launch_bounds__(256) void kfinal(const int* __restrict__ action,
                                              float* __restrict__ d_out)
{
  const int b = blockIdx.x, t = threadIdx.x;
  const float* lrow = d_out + (long)b * ADIM;
  __shared__ float sM[4], sS[4], sT[4];

  const float x0 = lrow[t], x1 = lrow[t + 256];
  float m = fmaxf(x0, x1);
#pragma unroll
  for (int s = 1; s < 64; s <<= 1) m = fmaxf(m, __shfl_xor(m, s, 64));
  const int wv = t >> 6, ln = t & 63;
  if (ln == 0) sM[wv] = m;
  __syncthreads();
  m = fmaxf(fmaxf(sM[0], sM[1]), fmaxf(sM[2], sM[3]));

  const float d0 = x0 - m, d1 = x1 - m;
  const float e0 = expf(d0), e1 = expf(d1);
  float s1 = e0 + e1;
  float s2 = e0 * d0 + e1 * d1;
#pragma unroll
  for (int s = 1; s < 64; s <<= 1) {
    s1 += __shfl_xor(s1, s, 64);
    s2 += __shfl_xor(s2, s, 64);
  }
  if (ln == 0) { sS[wv] = s1; sT[wv] = s2; }
  __syncthreads();
  if (t == 0) {
    const float S = sS[0] + sS[1] + sS[2] + sS[3];
    const float T = sT[0] + sT[1] + sT[2] + sT[3];
    const float lnS = logf(S);
    const int a = action[b];
    d_out[131328 + b] = (lrow[a] - m) - lnS;   // log_prob
    d_out[131584 + b] = lnS - T / S;           // entropy
  }
}

extern "C" void kernel_launch(void* const* d_in, const int* in_sizes, int n_in,
                              void* d_out_v, int out_size, void* d_ws, size_t ws_size,
                              hipStream_t stream) {
  const float* obs   = (const float*)d_in[0];
  const float* task  = (const float*)d_in[1];
  const int*   action= (const int*)  d_in[2];
  const float* we1   = (const float*)d_in[3];
  const float* be1   = (const float*)d_in[4];
  const float* we2   = (const float*)d_in[5];
  const float* be2   = (const float*)d_in[6];
  const float* aw1   = (const float*)d_in[7];
  const float* aw1b  = (const float*)d_in[8];
  const float* aw2   = (const float*)d_in[9];
  const float* aw2b  = (const float*)d_in[10];
  const float* ab1   = (const float*)d_in[11];
  const float* ab1b  = (const float*)d_in[12];
  const float* ab2   = (const float*)d_in[13];
  const float* ab2b  = (const float*)d_in[14];
  const float* cw1   = (const float*)d_in[15];
  const float* cw1b  = (const float*)d_in[16];
  const float* cw2   = (const float*)d_in[17];
  const float* cw2b  = (const float*)d_in[18];
  const float* cb1   = (const float*)d_in[19];
  const float* cb1b  = (const float*)d_in[20];
  const float* cb2   = (const float*)d_in[21];
  const float* cb2b  = (const float*)d_in[22];
  float* out = (float*)d_out_v;
  float* ws_ha = (float*)d_ws;            // [256][128] f32
  float* ws_hc = ws_ha + 256 * 128;       // [256][128] f32

  kprep<<<256, 128, 0, stream>>>(task, action, we1, be1, we2, be2, aw1, aw1b,
                                 ab1, ab1b, ab2, ab2b, cw1, cw1b, cb1, cb1b,
                                 cb2, cb2b, ws_ha, ws_hc, out);
  khyper<<<513, 512, 0, stream>>>(obs, aw2, aw2b, cw2, cw2b, ws_ha, ws_hc, out);
  kfinal<<<256, 256, 0, stream>>>(action, out);
}